// Round 1
// baseline (5558.632 us; speedup 1.0000x reference)
//
#include <hip/hip_runtime.h>

#define NN 100000
#define NE 1600000
#define HID 64

// ---------------- Edge MLP + scatter-add ----------------
// one thread per edge; W1a/W1b staged in LDS (wave-uniform broadcast reads)
__global__ __launch_bounds__(256) void edge_mlp_scatter(
    const float* __restrict__ x,      // [N,32]
    const int*   __restrict__ ei,     // [2,E] flat
    const float* __restrict__ ea,     // [E,32]
    const float* __restrict__ W1a,    // [64,64]
    const float* __restrict__ b1a,    // [64]
    const float* __restrict__ W1b,    // [64,64]
    const float* __restrict__ b1b,    // [64]
    float* __restrict__ summed,       // [N,64] (zeroed)
    float* __restrict__ counts,       // [N]    (zeroed)
    int E)
{
    __shared__ float sW1a[64 * HID];
    __shared__ float sW1b[HID * HID];
    __shared__ float sb1a[HID];
    __shared__ float sb1b[HID];
    for (int i = threadIdx.x; i < 64 * HID; i += 256) {
        sW1a[i] = W1a[i];
        sW1b[i] = W1b[i];
    }
    if (threadIdx.x < HID) {
        sb1a[threadIdx.x] = b1a[threadIdx.x];
        sb1b[threadIdx.x] = b1b[threadIdx.x];
    }
    __syncthreads();

    int e = blockIdx.x * 256 + threadIdx.x;
    if (e >= E) return;

    int row = ei[e];
    int col = ei[E + e];

    // ---- layer 1: h1 = relu([x[col], ea[e]] @ W1a + b1a) ----
    float h1[HID];
    #pragma unroll
    for (int j = 0; j < HID; ++j) h1[j] = sb1a[j];

    const float* __restrict__ xrow = x + (size_t)col * 32;
    #pragma unroll 2
    for (int k4 = 0; k4 < 8; ++k4) {
        float4 v = *(const float4*)(xrow + k4 * 4);
        float vv[4] = {v.x, v.y, v.z, v.w};
        #pragma unroll
        for (int kk = 0; kk < 4; ++kk) {
            const float* wr = &sW1a[(k4 * 4 + kk) * HID];
            float val = vv[kk];
            #pragma unroll
            for (int j = 0; j < HID; j += 4) {
                float4 w = *(const float4*)(wr + j);
                h1[j + 0] += val * w.x;
                h1[j + 1] += val * w.y;
                h1[j + 2] += val * w.z;
                h1[j + 3] += val * w.w;
            }
        }
    }
    const float* __restrict__ earow = ea + (size_t)e * 32;
    #pragma unroll 2
    for (int k4 = 0; k4 < 8; ++k4) {
        float4 v = *(const float4*)(earow + k4 * 4);
        float vv[4] = {v.x, v.y, v.z, v.w};
        #pragma unroll
        for (int kk = 0; kk < 4; ++kk) {
            const float* wr = &sW1a[(32 + k4 * 4 + kk) * HID];
            float val = vv[kk];
            #pragma unroll
            for (int j = 0; j < HID; j += 4) {
                float4 w = *(const float4*)(wr + j);
                h1[j + 0] += val * w.x;
                h1[j + 1] += val * w.y;
                h1[j + 2] += val * w.z;
                h1[j + 3] += val * w.w;
            }
        }
    }
    #pragma unroll
    for (int j = 0; j < HID; ++j) h1[j] = fmaxf(h1[j], 0.0f);

    // ---- layer 2: m = h1 @ W1b + b1b, scatter-add to summed[row] ----
    // two 32-wide halves to cap register pressure
    float* __restrict__ srow = summed + (size_t)row * HID;
    #pragma unroll
    for (int half = 0; half < 2; ++half) {
        float m[32];
        #pragma unroll
        for (int j = 0; j < 32; ++j) m[j] = sb1b[half * 32 + j];
        #pragma unroll
        for (int k = 0; k < HID; ++k) {
            float val = h1[k];
            const float* wr = &sW1b[k * HID + half * 32];
            #pragma unroll
            for (int j = 0; j < 32; j += 4) {
                float4 w = *(const float4*)(wr + j);
                m[j + 0] += val * w.x;
                m[j + 1] += val * w.y;
                m[j + 2] += val * w.z;
                m[j + 3] += val * w.w;
            }
        }
        #pragma unroll
        for (int j = 0; j < 32; ++j) atomicAdd(&srow[half * 32 + j], m[j]);
    }
    atomicAdd(&counts[row], 1.0f);
}

// ---------------- Node MLP ----------------
__global__ __launch_bounds__(256) void node_mlp(
    const float* __restrict__ x,       // [N,32]
    const float* __restrict__ summed,  // [N,64]
    const float* __restrict__ counts,  // [N]
    const float* __restrict__ W2a,     // [96,64]
    const float* __restrict__ b2a,     // [64]
    const float* __restrict__ W2b,     // [64,32]
    const float* __restrict__ b2b,     // [32]
    float* __restrict__ out,           // [N,32]
    int N)
{
    __shared__ float sW2a[96 * 64];
    __shared__ float sW2b[64 * 32];
    __shared__ float sb2a[64];
    __shared__ float sb2b[32];
    for (int i = threadIdx.x; i < 96 * 64; i += 256) sW2a[i] = W2a[i];
    for (int i = threadIdx.x; i < 64 * 32; i += 256) sW2b[i] = W2b[i];
    if (threadIdx.x < 64) sb2a[threadIdx.x] = b2a[threadIdx.x];
    if (threadIdx.x < 32) sb2b[threadIdx.x] = b2b[threadIdx.x];
    __syncthreads();

    int i = blockIdx.x * 256 + threadIdx.x;
    if (i >= N) return;

    float inv = 1.0f / fmaxf(counts[i], 1.0f);

    float h2[64];
    #pragma unroll
    for (int j = 0; j < 64; ++j) h2[j] = sb2a[j];

    // x part (rows 0..31 of W2a)
    const float* __restrict__ xrow = x + (size_t)i * 32;
    #pragma unroll 2
    for (int k4 = 0; k4 < 8; ++k4) {
        float4 v = *(const float4*)(xrow + k4 * 4);
        float vv[4] = {v.x, v.y, v.z, v.w};
        #pragma unroll
        for (int kk = 0; kk < 4; ++kk) {
            const float* wr = &sW2a[(k4 * 4 + kk) * 64];
            float val = vv[kk];
            #pragma unroll
            for (int j = 0; j < 64; j += 4) {
                float4 w = *(const float4*)(wr + j);
                h2[j + 0] += val * w.x;
                h2[j + 1] += val * w.y;
                h2[j + 2] += val * w.z;
                h2[j + 3] += val * w.w;
            }
        }
    }
    // agg part (rows 32..95 of W2a)
    const float* __restrict__ srow = summed + (size_t)i * 64;
    #pragma unroll 2
    for (int k4 = 0; k4 < 16; ++k4) {
        float4 v = *(const float4*)(srow + k4 * 4);
        float vv[4] = {v.x * inv, v.y * inv, v.z * inv, v.w * inv};
        #pragma unroll
        for (int kk = 0; kk < 4; ++kk) {
            const float* wr = &sW2a[(32 + k4 * 4 + kk) * 64];
            float val = vv[kk];
            #pragma unroll
            for (int j = 0; j < 64; j += 4) {
                float4 w = *(const float4*)(wr + j);
                h2[j + 0] += val * w.x;
                h2[j + 1] += val * w.y;
                h2[j + 2] += val * w.z;
                h2[j + 3] += val * w.w;
            }
        }
    }
    #pragma unroll
    for (int j = 0; j < 64; ++j) h2[j] = fmaxf(h2[j], 0.0f);

    // out = h2 @ W2b + b2b
    float o[32];
    #pragma unroll
    for (int j = 0; j < 32; ++j) o[j] = sb2b[j];
    #pragma unroll
    for (int k = 0; k < 64; ++k) {
        float val = h2[k];
        const float* wr = &sW2b[k * 32];
        #pragma unroll
        for (int j = 0; j < 32; j += 4) {
            float4 w = *(const float4*)(wr + j);
            o[j + 0] += val * w.x;
            o[j + 1] += val * w.y;
            o[j + 2] += val * w.z;
            o[j + 3] += val * w.w;
        }
    }
    float* __restrict__ orow = out + (size_t)i * 32;
    #pragma unroll
    for (int j = 0; j < 32; j += 4) {
        *(float4*)(orow + j) = make_float4(o[j], o[j + 1], o[j + 2], o[j + 3]);
    }
}

extern "C" void kernel_launch(void* const* d_in, const int* in_sizes, int n_in,
                              void* d_out, int out_size, void* d_ws, size_t ws_size,
                              hipStream_t stream) {
    const float* x   = (const float*)d_in[0];
    const int*   ei  = (const int*)d_in[1];
    const float* ea  = (const float*)d_in[2];
    // d_in[3] = u (unused), d_in[4] = batch (unused)
    const float* W1a = (const float*)d_in[5];
    const float* b1a = (const float*)d_in[6];
    const float* W1b = (const float*)d_in[7];
    const float* b1b = (const float*)d_in[8];
    const float* W2a = (const float*)d_in[9];
    const float* b2a = (const float*)d_in[10];
    const float* W2b = (const float*)d_in[11];
    const float* b2b = (const float*)d_in[12];
    float* out = (float*)d_out;

    const int N = NN;
    const int E = NE;

    float* summed = (float*)d_ws;          // [N*64]
    float* counts = summed + (size_t)N * HID;  // [N]

    size_t zero_bytes = (size_t)N * (HID + 1) * sizeof(float);
    hipMemsetAsync(d_ws, 0, zero_bytes, stream);

    dim3 blk(256);
    dim3 grid_e((E + 255) / 256);
    hipLaunchKernelGGL(edge_mlp_scatter, grid_e, blk, 0, stream,
                       x, ei, ea, W1a, b1a, W1b, b1b, summed, counts, E);

    dim3 grid_n((N + 255) / 256);
    hipLaunchKernelGGL(node_mlp, grid_n, blk, 0, stream,
                       x, summed, counts, W2a, b2a, W2b, b2b, out, N);
}